// Round 1
// baseline (932.434 us; speedup 1.0000x reference)
//
#include <hip/hip_runtime.h>

#define B_ 32
#define S_ 512
#define E_ 1024
#define P_ 256
#define HH 8
// rows = B*S = 16384

// ---------------- stage 0: repack conv_w (O,I,K) -> Wt[k*256+i][o] ----------------
__global__ __launch_bounds__(256) void k_wt(const float* __restrict__ cw,
                                            float* __restrict__ wt) {
  int idx = blockIdx.x * 256 + threadIdx.x;      // 768*256 total
  int o = idx & 255;
  int kidx = idx >> 8;                            // k*256+i
  int k = kidx >> 8, i = kidx & 255;
  wt[idx] = cw[o * 768 + i * 3 + k];
}

// ---------------- stage 1: proj = x @ proj_w + proj_b  (16384x1024x256) ----------
// 128x128 block tile, 256 threads, 8x8 per thread, K-chunk 16
__global__ __launch_bounds__(256) void k_proj(const float* __restrict__ x,
                                              const float* __restrict__ pw,
                                              const float* __restrict__ pb,
                                              float* __restrict__ proj) {
  __shared__ float As[16][132];
  __shared__ float Bs[16][132];
  const int m0 = blockIdx.x * 128;
  const int n0 = blockIdx.y * 128;
  const int t = threadIdx.x;
  const int tx = t & 15, ty = t >> 4;
  float acc[8][8];
#pragma unroll
  for (int i = 0; i < 8; i++)
#pragma unroll
    for (int j = 0; j < 8; j++) acc[i][j] = 0.f;

  for (int kc = 0; kc < E_; kc += 16) {
#pragma unroll
    for (int q = 0; q < 2; q++) {
      int f = t + q * 256;
      int r = f >> 2, k4 = (f & 3) * 4;
      float4 v = *(const float4*)(x + (m0 + r) * E_ + kc + k4);
      As[k4 + 0][r] = v.x; As[k4 + 1][r] = v.y;
      As[k4 + 2][r] = v.z; As[k4 + 3][r] = v.w;
    }
#pragma unroll
    for (int q = 0; q < 2; q++) {
      int f = t + q * 256;
      int kk = f >> 5, n4 = (f & 31) * 4;
      *(float4*)&Bs[kk][n4] = *(const float4*)(pw + (kc + kk) * P_ + n0 + n4);
    }
    __syncthreads();
#pragma unroll
    for (int kk = 0; kk < 16; kk++) {
      float a[8], b[8];
      *(float4*)(a)     = *(const float4*)&As[kk][ty * 8];
      *(float4*)(a + 4) = *(const float4*)&As[kk][ty * 8 + 4];
      *(float4*)(b)     = *(const float4*)&Bs[kk][tx * 8];
      *(float4*)(b + 4) = *(const float4*)&Bs[kk][tx * 8 + 4];
#pragma unroll
      for (int i = 0; i < 8; i++)
#pragma unroll
        for (int j = 0; j < 8; j++) acc[i][j] += a[i] * b[j];
    }
    __syncthreads();
  }
#pragma unroll
  for (int i = 0; i < 8; i++) {
    int row = m0 + ty * 8 + i;
    int col = n0 + tx * 8;
    float4 v0, v1;
    v0.x = acc[i][0] + pb[col + 0]; v0.y = acc[i][1] + pb[col + 1];
    v0.z = acc[i][2] + pb[col + 2]; v0.w = acc[i][3] + pb[col + 3];
    v1.x = acc[i][4] + pb[col + 4]; v1.y = acc[i][5] + pb[col + 5];
    v1.z = acc[i][6] + pb[col + 6]; v1.w = acc[i][7] + pb[col + 7];
    *(float4*)(proj + row * P_ + col) = v0;
    *(float4*)(proj + row * P_ + col + 4) = v1;
  }
}

// ---------------- stage 2: conv-as-GEMM -> rep_conv (16384x768x256) --------------
// A[row=(b,s)][kidx=k*256+i] = proj[b, s+k, i] for s in [1,509], else 0
// 64x128 block tile, 256 threads (16x16), 4x8 per thread, K-chunk 16
__global__ __launch_bounds__(256) void k_conv(const float* __restrict__ proj,
                                              const float* __restrict__ wt,
                                              const float* __restrict__ cb,
                                              const int* __restrict__ seq,
                                              float* __restrict__ rep) {
  __shared__ float As[16][68];
  __shared__ float Bs[16][132];
  const int m0 = blockIdx.x * 64;
  const int n0 = blockIdx.y * 128;
  const int t = threadIdx.x;
  const int tx = t & 15, ty = t >> 4;
  float acc[4][8];
#pragma unroll
  for (int i = 0; i < 4; i++)
#pragma unroll
    for (int j = 0; j < 8; j++) acc[i][j] = 0.f;

  for (int kc = 0; kc < 768; kc += 16) {
    {
      int r = t >> 2, k4 = (t & 3) * 4;
      int rm = m0 + r;
      int bb = rm >> 9, s = rm & 511;
      int kg = kc + k4;
      int k = kg >> 8, i = kg & 255;
      float4 v = make_float4(0.f, 0.f, 0.f, 0.f);
      if (s >= 1 && s <= 509)
        v = *(const float4*)(proj + (bb * S_ + s + k) * P_ + i);
      As[k4 + 0][r] = v.x; As[k4 + 1][r] = v.y;
      As[k4 + 2][r] = v.z; As[k4 + 3][r] = v.w;
    }
#pragma unroll
    for (int q = 0; q < 2; q++) {
      int f = t + q * 256;
      int kk = f >> 5, n4 = (f & 31) * 4;
      *(float4*)&Bs[kk][n4] = *(const float4*)(wt + (kc + kk) * P_ + n0 + n4);
    }
    __syncthreads();
#pragma unroll
    for (int kk = 0; kk < 16; kk++) {
      float a[4], b[8];
      *(float4*)(a)     = *(const float4*)&As[kk][ty * 4];
      *(float4*)(b)     = *(const float4*)&Bs[kk][tx * 8];
      *(float4*)(b + 4) = *(const float4*)&Bs[kk][tx * 8 + 4];
#pragma unroll
      for (int i = 0; i < 4; i++)
#pragma unroll
        for (int j = 0; j < 8; j++) acc[i][j] += a[i] * b[j];
    }
    __syncthreads();
  }
#pragma unroll
  for (int i = 0; i < 4; i++) {
    int rm = m0 + ty * 4 + i;
    int bb = rm >> 9, s = rm & 511;
    int l = seq[bb];
    bool valid = (s >= 1) && (s <= 509) && (s < l - 1);
    int col = n0 + tx * 8;
    float4 v0, v1;
    float r0 = fmaxf(acc[i][0] + cb[col + 0], 0.f);
    float r1 = fmaxf(acc[i][1] + cb[col + 1], 0.f);
    float r2 = fmaxf(acc[i][2] + cb[col + 2], 0.f);
    float r3 = fmaxf(acc[i][3] + cb[col + 3], 0.f);
    float r4 = fmaxf(acc[i][4] + cb[col + 4], 0.f);
    float r5 = fmaxf(acc[i][5] + cb[col + 5], 0.f);
    float r6 = fmaxf(acc[i][6] + cb[col + 6], 0.f);
    float r7 = fmaxf(acc[i][7] + cb[col + 7], 0.f);
    float m = valid ? 1.f : 0.f;
    v0.x = r0 * m; v0.y = r1 * m; v0.z = r2 * m; v0.w = r3 * m;
    v1.x = r4 * m; v1.y = r5 * m; v1.z = r6 * m; v1.w = r7 * m;
    *(float4*)(rep + rm * P_ + col) = v0;
    *(float4*)(rep + rm * P_ + col + 4) = v1;
  }
}

// ---------------- stage 3: fused logits GEMM + exp + h-fold ----------------------
// E[row][q] = sum_h exp( rep[row,:] . attn_w[:, h*512+q] + attn_b[h*512+q] )
// 64 rows x 128 q block tile, full A (K=256) staged once, loop h=0..7
__global__ __launch_bounds__(256) void k_attn(const float* __restrict__ rep,
                                              const float* __restrict__ aw,
                                              const float* __restrict__ ab,
                                              float* __restrict__ Efold) {
  __shared__ float As[256][68];
  __shared__ float Bs[16][132];
  const int m0 = blockIdx.x * 64;
  const int q0 = blockIdx.y * 128;
  const int t = threadIdx.x;
  const int tx = t & 15, ty = t >> 4;

  // stage full A tile: 64 rows x 256 k
#pragma unroll
  for (int c = 0; c < 16; c++) {
    int f = c * 256 + t;
    int r = f >> 6;
    int k4 = (t & 63) * 4;
    float4 v = *(const float4*)(rep + (m0 + r) * P_ + k4);
    As[k4 + 0][r] = v.x; As[k4 + 1][r] = v.y;
    As[k4 + 2][r] = v.z; As[k4 + 3][r] = v.w;
  }

  float ef[4][8];
#pragma unroll
  for (int i = 0; i < 4; i++)
#pragma unroll
    for (int j = 0; j < 8; j++) ef[i][j] = 0.f;

  for (int h = 0; h < HH; h++) {
    float acc[4][8];
#pragma unroll
    for (int i = 0; i < 4; i++)
#pragma unroll
      for (int j = 0; j < 8; j++) acc[i][j] = 0.f;

    for (int kc = 0; kc < 16; kc++) {
      __syncthreads();
#pragma unroll
      for (int q = 0; q < 2; q++) {
        int f = t + q * 256;
        int kk = f >> 5, n4 = (f & 31) * 4;
        *(float4*)&Bs[kk][n4] =
            *(const float4*)(aw + (kc * 16 + kk) * 4096 + h * 512 + q0 + n4);
      }
      __syncthreads();
#pragma unroll
      for (int kk = 0; kk < 16; kk++) {
        float a[4], b[8];
        *(float4*)(a)     = *(const float4*)&As[kc * 16 + kk][ty * 4];
        *(float4*)(b)     = *(const float4*)&Bs[kk][tx * 8];
        *(float4*)(b + 4) = *(const float4*)&Bs[kk][tx * 8 + 4];
#pragma unroll
        for (int i = 0; i < 4; i++)
#pragma unroll
          for (int j = 0; j < 8; j++) acc[i][j] += a[i] * b[j];
      }
    }
    float eb[8];
#pragma unroll
    for (int j = 0; j < 8; j++) eb[j] = ab[h * 512 + q0 + tx * 8 + j];
#pragma unroll
    for (int i = 0; i < 4; i++)
#pragma unroll
      for (int j = 0; j < 8; j++) ef[i][j] += __expf(acc[i][j] + eb[j]);
  }
#pragma unroll
  for (int i = 0; i < 4; i++) {
    int rm = m0 + ty * 4 + i;
    int col = q0 + tx * 8;
    *(float4*)(Efold + rm * 512 + col)     = *(float4*)&ef[i][0];
    *(float4*)(Efold + rm * 512 + col + 4) = *(float4*)&ef[i][4];
  }
}

// ---------------- stage 4a: row sums Z[row] = sum_q E[row][q] --------------------
__global__ __launch_bounds__(256) void k_z(const float* __restrict__ E,
                                           float* __restrict__ Z) {
  int row = blockIdx.x * 4 + (threadIdx.x >> 6);
  int lane = threadIdx.x & 63;
  float s = 0.f;
#pragma unroll
  for (int j = 0; j < 8; j++) s += E[row * 512 + j * 64 + lane];
#pragma unroll
  for (int m = 32; m > 0; m >>= 1) s += __shfl_xor(s, m, 64);
  if (lane == 0) Z[row] = s;
}

// ---------------- stage 4b: w[b,q] = (1/H) sum_s E[b,s,q]/Z[b,s] -----------------
__global__ __launch_bounds__(512) void k_w(const float* __restrict__ E,
                                           const float* __restrict__ Z,
                                           float* __restrict__ wB) {
  __shared__ float rZ[512];
  int b = blockIdx.x, t = threadIdx.x;
  rZ[t] = 1.0f / Z[b * 512 + t];
  __syncthreads();
  float acc = 0.f;
  for (int s = 0; s < 512; s++) acc += E[(b * 512 + s) * 512 + t] * rZ[s];
  wB[b * 512 + t] = acc * (1.0f / HH);
}

// ---------------- stage 5: rep_attn -> heads -> probs + argmax -------------------
__global__ __launch_bounds__(256) void k_final(const float* __restrict__ rep,
                                               const float* __restrict__ wB,
                                               const float* __restrict__ c1w,
                                               const float* __restrict__ c1b,
                                               const float* __restrict__ c2w,
                                               const float* __restrict__ c2b,
                                               float* __restrict__ out) {
  __shared__ float wS[512];
  __shared__ float repA[256];
  __shared__ float hS[128];
  __shared__ float clsS[2];
  int b = blockIdx.x, t = threadIdx.x;
  wS[t] = wB[b * 512 + t];
  wS[t + 256] = wB[b * 512 + t + 256];
  __syncthreads();
  {
    float acc = 0.f;
    for (int q = 0; q < 512; q++) acc += wS[q] * rep[(b * S_ + q) * P_ + t];
    repA[t] = acc;
  }
  __syncthreads();
  if (t < 128) {
    float acc = c1b[t];
    for (int p = 0; p < 256; p++) acc += repA[p] * c1w[p * 128 + t];
    hS[t] = acc > 0.f ? acc : 0.01f * acc;
  }
  __syncthreads();
  if (t < 2) {
    float acc = c2b[t];
    for (int j = 0; j < 128; j++) acc += hS[j] * c2w[j * 2 + t];
    clsS[t] = acc;
  }
  __syncthreads();
  if (t == 0) {
    float c0 = clsS[0], c1 = clsS[1];
    float m = fmaxf(c0, c1);
    float e0 = __expf(c0 - m), e1 = __expf(c1 - m);
    float inv = 1.0f / (e0 + e1);
    float p0 = e0 * inv, p1 = e1 * inv;
    out[b * 2 + 0] = p0;
    out[b * 2 + 1] = p1;
    out[B_ * 2 + b] = (p1 > p0) ? 1.0f : 0.0f;  // argmax, first-max tie -> 0
  }
}

extern "C" void kernel_launch(void* const* d_in, const int* in_sizes, int n_in,
                              void* d_out, int out_size, void* d_ws, size_t ws_size,
                              hipStream_t stream) {
  const float* x   = (const float*)d_in[0];
  const int*   seq = (const int*)d_in[1];
  const float* pw  = (const float*)d_in[2];
  const float* pb  = (const float*)d_in[3];
  const float* cw  = (const float*)d_in[4];
  const float* cb  = (const float*)d_in[5];
  const float* aw  = (const float*)d_in[6];
  const float* ab  = (const float*)d_in[7];
  const float* c1w = (const float*)d_in[8];
  const float* c1b = (const float*)d_in[9];
  const float* c2w = (const float*)d_in[10];
  const float* c2b = (const float*)d_in[11];
  float* out = (float*)d_out;

  char* ws = (char*)d_ws;
  float* proj = (float*)(ws);                       // 16384*256*4 = 16 MiB
  float* rep  = (float*)(ws + (size_t)16777216);    // 16 MiB
  float* E    = (float*)(ws + (size_t)33554432);    // 32 MiB
  float* wt   = (float*)(ws + (size_t)67108864);    // 768 KiB
  float* Z    = (float*)(ws + (size_t)67895296);    // 64 KiB
  float* wB   = (float*)(ws + (size_t)67960832);    // 64 KiB

  k_wt<<<768, 256, 0, stream>>>(cw, wt);
  k_proj<<<dim3(128, 2), 256, 0, stream>>>(x, pw, pb, proj);
  k_conv<<<dim3(256, 2), 256, 0, stream>>>(proj, wt, cb, seq, rep);
  k_attn<<<dim3(256, 4), 256, 0, stream>>>(rep, aw, ab, E);
  k_z<<<4096, 256, 0, stream>>>(E, Z);
  k_w<<<32, 512, 0, stream>>>(E, Z, wB);
  k_final<<<32, 256, 0, stream>>>(rep, wB, c1w, c1b, c2w, c2b, out);
}

// Round 2
// 448.044 us; speedup vs baseline: 2.0811x; 2.0811x over previous
//
#include <hip/hip_runtime.h>

#define B_ 32
#define S_ 512
#define E_ 1024
#define P_ 256
#define HH 8
// rows = B*S = 16384

typedef __attribute__((ext_vector_type(8))) short bf16x8;
typedef __attribute__((ext_vector_type(8))) unsigned short ushort8;
typedef __attribute__((ext_vector_type(16))) float f32x16;

static __device__ __forceinline__ unsigned short f2bf(float f) {
  union { float f; unsigned int u; } v;
  v.f = f;
  unsigned int r = (v.u + 0x7FFFu + ((v.u >> 16) & 1u)) >> 16;
  return (unsigned short)r;
}

// ---------------- stage 0a: repack conv_w (O,I,K) -> Wt[k*256+i][o] ---------------
__global__ __launch_bounds__(256) void k_wt(const float* __restrict__ cw,
                                            float* __restrict__ wt) {
  int idx = blockIdx.x * 256 + threadIdx.x;      // 768*256 total
  int o = idx & 255;
  int kidx = idx >> 8;                            // k*256+i
  int k = kidx >> 8, i = kidx & 255;
  wt[idx] = cw[o * 768 + i * 3 + k];
}

// ---------------- stage 0b: transpose+cast attn_w [k][j] -> awT[j][k] bf16 --------
__global__ __launch_bounds__(256) void k_awT(const float* __restrict__ aw,
                                             unsigned short* __restrict__ awT) {
  __shared__ float T[32][33];
  int j0 = blockIdx.x * 32;   // 128 blocks
  int k0 = blockIdx.y * 32;   // 8 blocks
  int tx = threadIdx.x & 31, ty = threadIdx.x >> 5;  // ty 0..7
#pragma unroll
  for (int i = 0; i < 4; i++) {
    int k = k0 + ty + i * 8;
    T[ty + i * 8][tx] = aw[k * 4096 + j0 + tx];
  }
  __syncthreads();
#pragma unroll
  for (int i = 0; i < 4; i++) {
    int j = j0 + ty + i * 8;
    awT[j * 256 + k0 + tx] = f2bf(T[tx][ty + i * 8]);
  }
}

// ---------------- stage 1: proj = x @ proj_w + proj_b  (16384x1024x256) ----------
__global__ __launch_bounds__(256) void k_proj(const float* __restrict__ x,
                                              const float* __restrict__ pw,
                                              const float* __restrict__ pb,
                                              float* __restrict__ proj) {
  __shared__ float As[16][132];
  __shared__ float Bs[16][132];
  const int m0 = blockIdx.x * 128;
  const int n0 = blockIdx.y * 128;
  const int t = threadIdx.x;
  const int tx = t & 15, ty = t >> 4;
  float acc[8][8];
#pragma unroll
  for (int i = 0; i < 8; i++)
#pragma unroll
    for (int j = 0; j < 8; j++) acc[i][j] = 0.f;

  for (int kc = 0; kc < E_; kc += 16) {
#pragma unroll
    for (int q = 0; q < 2; q++) {
      int f = t + q * 256;
      int r = f >> 2, k4 = (f & 3) * 4;
      float4 v = *(const float4*)(x + (m0 + r) * E_ + kc + k4);
      As[k4 + 0][r] = v.x; As[k4 + 1][r] = v.y;
      As[k4 + 2][r] = v.z; As[k4 + 3][r] = v.w;
    }
#pragma unroll
    for (int q = 0; q < 2; q++) {
      int f = t + q * 256;
      int kk = f >> 5, n4 = (f & 31) * 4;
      *(float4*)&Bs[kk][n4] = *(const float4*)(pw + (kc + kk) * P_ + n0 + n4);
    }
    __syncthreads();
#pragma unroll
    for (int kk = 0; kk < 16; kk++) {
      float a[8], b[8];
      *(float4*)(a)     = *(const float4*)&As[kk][ty * 8];
      *(float4*)(a + 4) = *(const float4*)&As[kk][ty * 8 + 4];
      *(float4*)(b)     = *(const float4*)&Bs[kk][tx * 8];
      *(float4*)(b + 4) = *(const float4*)&Bs[kk][tx * 8 + 4];
#pragma unroll
      for (int i = 0; i < 8; i++)
#pragma unroll
        for (int j = 0; j < 8; j++) acc[i][j] += a[i] * b[j];
    }
    __syncthreads();
  }
#pragma unroll
  for (int i = 0; i < 8; i++) {
    int row = m0 + ty * 8 + i;
    int col = n0 + tx * 8;
    float4 v0, v1;
    v0.x = acc[i][0] + pb[col + 0]; v0.y = acc[i][1] + pb[col + 1];
    v0.z = acc[i][2] + pb[col + 2]; v0.w = acc[i][3] + pb[col + 3];
    v1.x = acc[i][4] + pb[col + 4]; v1.y = acc[i][5] + pb[col + 5];
    v1.z = acc[i][6] + pb[col + 6]; v1.w = acc[i][7] + pb[col + 7];
    *(float4*)(proj + row * P_ + col) = v0;
    *(float4*)(proj + row * P_ + col + 4) = v1;
  }
}

// ---------------- stage 2: conv-as-GEMM -> rep fp32 + rep bf16 -------------------
__global__ __launch_bounds__(256) void k_conv(const float* __restrict__ proj,
                                              const float* __restrict__ wt,
                                              const float* __restrict__ cb,
                                              const int* __restrict__ seq,
                                              float* __restrict__ rep,
                                              unsigned short* __restrict__ rep16) {
  __shared__ float As[16][68];
  __shared__ float Bs[16][132];
  const int m0 = blockIdx.x * 64;
  const int n0 = blockIdx.y * 128;
  const int t = threadIdx.x;
  const int tx = t & 15, ty = t >> 4;
  float acc[4][8];
#pragma unroll
  for (int i = 0; i < 4; i++)
#pragma unroll
    for (int j = 0; j < 8; j++) acc[i][j] = 0.f;

  for (int kc = 0; kc < 768; kc += 16) {
    {
      int r = t >> 2, k4 = (t & 3) * 4;
      int rm = m0 + r;
      int bb = rm >> 9, s = rm & 511;
      int kg = kc + k4;
      int k = kg >> 8, i = kg & 255;
      float4 v = make_float4(0.f, 0.f, 0.f, 0.f);
      if (s >= 1 && s <= 509)
        v = *(const float4*)(proj + (bb * S_ + s + k) * P_ + i);
      As[k4 + 0][r] = v.x; As[k4 + 1][r] = v.y;
      As[k4 + 2][r] = v.z; As[k4 + 3][r] = v.w;
    }
#pragma unroll
    for (int q = 0; q < 2; q++) {
      int f = t + q * 256;
      int kk = f >> 5, n4 = (f & 31) * 4;
      *(float4*)&Bs[kk][n4] = *(const float4*)(wt + (kc + kk) * P_ + n0 + n4);
    }
    __syncthreads();
#pragma unroll
    for (int kk = 0; kk < 16; kk++) {
      float a[4], b[8];
      *(float4*)(a)     = *(const float4*)&As[kk][ty * 4];
      *(float4*)(b)     = *(const float4*)&Bs[kk][tx * 8];
      *(float4*)(b + 4) = *(const float4*)&Bs[kk][tx * 8 + 4];
#pragma unroll
      for (int i = 0; i < 4; i++)
#pragma unroll
        for (int j = 0; j < 8; j++) acc[i][j] += a[i] * b[j];
    }
    __syncthreads();
  }
#pragma unroll
  for (int i = 0; i < 4; i++) {
    int rm = m0 + ty * 4 + i;
    int bb = rm >> 9, s = rm & 511;
    int l = seq[bb];
    bool valid = (s >= 1) && (s <= 509) && (s < l - 1);
    int col = n0 + tx * 8;
    float m = valid ? 1.f : 0.f;
    float r[8];
#pragma unroll
    for (int j = 0; j < 8; j++) r[j] = fmaxf(acc[i][j] + cb[col + j], 0.f) * m;
    float4 v0, v1;
    v0.x = r[0]; v0.y = r[1]; v0.z = r[2]; v0.w = r[3];
    v1.x = r[4]; v1.y = r[5]; v1.z = r[6]; v1.w = r[7];
    *(float4*)(rep + rm * P_ + col) = v0;
    *(float4*)(rep + rm * P_ + col + 4) = v1;
    ushort8 h;
#pragma unroll
    for (int j = 0; j < 8; j++) h[j] = f2bf(r[j]);
    *(ushort8*)(rep16 + rm * P_ + col) = h;
  }
}

// ---------------- stage 3: MFMA logits GEMM + exp + h-fold -----------------------
// E[row][q] = sum_h exp( rep[row,:] . awT[h*512+q,:] + ab[h*512+q] )
// block: 64 rows x 128 q. 4 waves, each 64 rows x 32 q. A in LDS (staged once,
// barrier-free K-loop); B frags loaded register-direct from L2-resident awT.
__global__ __launch_bounds__(256) void k_attn_mfma(const unsigned short* __restrict__ rep16,
                                                   const unsigned short* __restrict__ awT,
                                                   const float* __restrict__ ab,
                                                   float* __restrict__ E) {
  __shared__ unsigned short As[64][264];  // stride 528B: 16B-aligned rows
  const int m0 = blockIdx.x * 64;
  const int q0 = blockIdx.y * 128;
  const int t = threadIdx.x;
  const int w = t >> 6;          // wave 0..3
  const int lane = t & 63;
  const int ln31 = lane & 31;
  const int khalf = (lane >> 5) * 8;

  // stage A: 64 rows x 256 k (bf16) = 32 KB
#pragma unroll
  for (int i = 0; i < 8; i++) {
    int flat = i * 256 + t;
    int r = flat >> 5;
    int g = (flat & 31) * 8;
    ushort8 v = *(const ushort8*)(rep16 + (m0 + r) * 256 + g);
    *(ushort8*)&As[r][g] = v;
  }
  __syncthreads();

  const int qcol = q0 + w * 32 + ln31;
  const unsigned short* bcol = awT + (size_t)qcol * 256 + khalf;

  float ef0[16], ef1[16];
#pragma unroll
  for (int r = 0; r < 16; r++) { ef0[r] = 0.f; ef1[r] = 0.f; }

  for (int h = 0; h < HH; h++) {
    const unsigned short* bh = bcol + (size_t)h * 512 * 256;
    f32x16 acc0, acc1;
#pragma unroll
    for (int r = 0; r < 16; r++) { acc0[r] = 0.f; acc1[r] = 0.f; }

#pragma unroll
    for (int kc = 0; kc < 256; kc += 16) {
      bf16x8 a0 = *(const bf16x8*)&As[ln31][kc + khalf];
      bf16x8 a1 = *(const bf16x8*)&As[32 + ln31][kc + khalf];
      bf16x8 b  = *(const bf16x8*)(bh + kc);
      acc0 = __builtin_amdgcn_mfma_f32_32x32x16_bf16(a0, b, acc0, 0, 0, 0);
      acc1 = __builtin_amdgcn_mfma_f32_32x32x16_bf16(a1, b, acc1, 0, 0, 0);
    }
    float bias = ab[h * 512 + qcol];
#pragma unroll
    for (int r = 0; r < 16; r++) {
      ef0[r] += __expf(acc0[r] + bias);
      ef1[r] += __expf(acc1[r] + bias);
    }
  }
  // store: row = m0 + tile*32 + (reg&3) + 8*(reg>>2) + 4*(lane>>5), col = qcol
  const int rbase = m0 + 4 * (lane >> 5);
#pragma unroll
  for (int r = 0; r < 16; r++) {
    int row0 = rbase + (r & 3) + 8 * (r >> 2);
    E[(size_t)row0 * 512 + qcol] = ef0[r];
    E[(size_t)(row0 + 32) * 512 + qcol] = ef1[r];
  }
}

// ---------------- stage 4a: row sums Z[row] = sum_q E[row][q] --------------------
__global__ __launch_bounds__(256) void k_z(const float* __restrict__ E,
                                           float* __restrict__ Z) {
  int row = blockIdx.x * 4 + (threadIdx.x >> 6);
  int lane = threadIdx.x & 63;
  float s = 0.f;
#pragma unroll
  for (int j = 0; j < 8; j++) s += E[row * 512 + j * 64 + lane];
#pragma unroll
  for (int m = 32; m > 0; m >>= 1) s += __shfl_xor(s, m, 64);
  if (lane == 0) Z[row] = s;
}

// ---------------- stage 4b: w[b,q] = (1/H) sum_s E[b,s,q]/Z[b,s] -----------------
__global__ __launch_bounds__(512) void k_wzero(float* __restrict__ wB) {
  wB[blockIdx.x * 512 + threadIdx.x] = 0.f;
}

__global__ __launch_bounds__(512) void k_w(const float* __restrict__ E,
                                           const float* __restrict__ Z,
                                           float* __restrict__ wB) {
  __shared__ float rZ[64];
  int b = blockIdx.x, c = blockIdx.y, t = threadIdx.x;
  int s0 = c * 64;
  if (t < 64) rZ[t] = 1.0f / Z[b * 512 + s0 + t];
  __syncthreads();
  float acc = 0.f;
  for (int s = 0; s < 64; s++) acc += E[(size_t)(b * 512 + s0 + s) * 512 + t] * rZ[s];
  atomicAdd(&wB[b * 512 + t], acc * (1.0f / HH));
}

// ---------------- stage 5: rep_attn -> heads -> probs + argmax -------------------
__global__ __launch_bounds__(256) void k_final(const float* __restrict__ rep,
                                               const float* __restrict__ wB,
                                               const float* __restrict__ c1w,
                                               const float* __restrict__ c1b,
                                               const float* __restrict__ c2w,
                                               const float* __restrict__ c2b,
                                               float* __restrict__ out) {
  __shared__ float wS[512];
  __shared__ float repA[256];
  __shared__ float hS[128];
  __shared__ float clsS[2];
  int b = blockIdx.x, t = threadIdx.x;
  wS[t] = wB[b * 512 + t];
  wS[t + 256] = wB[b * 512 + t + 256];
  __syncthreads();
  {
    float acc = 0.f;
    for (int q = 0; q < 512; q++) acc += wS[q] * rep[(b * S_ + q) * P_ + t];
    repA[t] = acc;
  }
  __syncthreads();
  if (t < 128) {
    float acc = c1b[t];
    for (int p = 0; p < 256; p++) acc += repA[p] * c1w[p * 128 + t];
    hS[t] = acc > 0.f ? acc : 0.01f * acc;
  }
  __syncthreads();
  if (t < 2) {
    float acc = c2b[t];
    for (int j = 0; j < 128; j++) acc += hS[j] * c2w[j * 2 + t];
    clsS[t] = acc;
  }
  __syncthreads();
  if (t == 0) {
    float c0 = clsS[0], c1 = clsS[1];
    float m = fmaxf(c0, c1);
    float e0 = __expf(c0 - m), e1 = __expf(c1 - m);
    float inv = 1.0f / (e0 + e1);
    float p0 = e0 * inv, p1 = e1 * inv;
    out[b * 2 + 0] = p0;
    out[b * 2 + 1] = p1;
    out[B_ * 2 + b] = (p1 > p0) ? 1.0f : 0.0f;
  }
}

extern "C" void kernel_launch(void* const* d_in, const int* in_sizes, int n_in,
                              void* d_out, int out_size, void* d_ws, size_t ws_size,
                              hipStream_t stream) {
  const float* x   = (const float*)d_in[0];
  const int*   seq = (const int*)d_in[1];
  const float* pw  = (const float*)d_in[2];
  const float* pb  = (const float*)d_in[3];
  const float* cw  = (const float*)d_in[4];
  const float* cb  = (const float*)d_in[5];
  const float* aw  = (const float*)d_in[6];
  const float* ab  = (const float*)d_in[7];
  const float* c1w = (const float*)d_in[8];
  const float* c1b = (const float*)d_in[9];
  const float* c2w = (const float*)d_in[10];
  const float* c2b = (const float*)d_in[11];
  float* out = (float*)d_out;

  char* ws = (char*)d_ws;
  // lifetimes: proj (k_proj->k_conv) overlaps E (written later in k_attn_mfma)
  float*          proj  = (float*)(ws);                       // 16 MiB, dies before E written
  float*          E     = (float*)(ws);                       // 32 MiB @ 0 (reuse)
  float*          rep   = (float*)(ws + (size_t)33554432);    // 16 MiB
  unsigned short* rep16 = (unsigned short*)(ws + (size_t)50331648);  // 8 MiB
  float*          wt    = (float*)(ws + (size_t)58720256);    // 768 KiB
  unsigned short* awT   = (unsigned short*)(ws + (size_t)59506688);  // 2 MiB
  float*          Z     = (float*)(ws + (size_t)61603840);    // 64 KiB
  float*          wB    = (float*)(ws + (size_t)61669376);    // 64 KiB

  k_wt<<<768, 256, 0, stream>>>(cw, wt);
  k_awT<<<dim3(128, 8), 256, 0, stream>>>(aw, awT);
  k_proj<<<dim3(128, 2), 256, 0, stream>>>(x, pw, pb, proj);
  k_conv<<<dim3(256, 2), 256, 0, stream>>>(proj, wt, cb, seq, rep, rep16);
  k_attn_mfma<<<dim3(256, 4), 256, 0, stream>>>(rep16, awT, ab, E);
  k_z<<<4096, 256, 0, stream>>>(E, Z);
  k_wzero<<<32, 512, 0, stream>>>(wB);
  k_w<<<dim3(32, 8), 512, 0, stream>>>(E, Z, wB);
  k_final<<<32, 256, 0, stream>>>(rep, wB, c1w, c1b, c2w, c2b, out);
}

// Round 3
// 253.747 us; speedup vs baseline: 3.6747x; 1.7657x over previous
//
#include <hip/hip_runtime.h>

#define B_ 32
#define S_ 512
#define E_ 1024
#define P_ 256
#define HH 8
// rows = B*S = 16384

typedef __attribute__((ext_vector_type(8))) short bf16x8;
typedef __attribute__((ext_vector_type(8))) unsigned short us8;
typedef __attribute__((ext_vector_type(4))) unsigned short us4;
typedef __attribute__((ext_vector_type(16))) float f32x16;

static __device__ __forceinline__ unsigned short f2bf(float f) {
  union { float f; unsigned int u; } v;
  v.f = f;
  unsigned int r = (v.u + 0x7FFFu + ((v.u >> 16) & 1u)) >> 16;
  return (unsigned short)r;
}
static __device__ __forceinline__ float bf2f(unsigned short u) {
  union { unsigned int u; float f; } v;
  v.u = ((unsigned int)u) << 16;
  return v.f;
}

// ---------------- stage 0a: conv_w (O,I,K) -> wtT[o][k*256+i] bf16 ---------------
__global__ __launch_bounds__(256) void k_wtT(const float* __restrict__ cw,
                                             unsigned short* __restrict__ wtT) {
  int o = blockIdx.x, k = blockIdx.y, i = threadIdx.x;
  wtT[o * 768 + k * 256 + i] = f2bf(cw[o * 768 + i * 3 + k]);
}

// ---------------- stage 0b: pw [k][n] -> pwT[n][k] bf16 --------------------------
__global__ __launch_bounds__(256) void k_pwT(const float* __restrict__ pw,
                                             unsigned short* __restrict__ pwT) {
  __shared__ float T[32][33];
  int n0 = blockIdx.x * 32;   // 8 blocks
  int k0 = blockIdx.y * 32;   // 32 blocks
  int tx = threadIdx.x & 31, ty = threadIdx.x >> 5;
#pragma unroll
  for (int i = 0; i < 4; i++)
    T[ty + i * 8][tx] = pw[(k0 + ty + i * 8) * P_ + n0 + tx];
  __syncthreads();
#pragma unroll
  for (int i = 0; i < 4; i++)
    pwT[(size_t)(n0 + ty + i * 8) * E_ + k0 + tx] = f2bf(T[tx][ty + i * 8]);
}

// ---------------- stage 0c: attn_w [k][j] -> awT[j][k] bf16 ----------------------
__global__ __launch_bounds__(256) void k_awT(const float* __restrict__ aw,
                                             unsigned short* __restrict__ awT) {
  __shared__ float T[32][33];
  int j0 = blockIdx.x * 32;   // 128 blocks
  int k0 = blockIdx.y * 32;   // 8 blocks
  int tx = threadIdx.x & 31, ty = threadIdx.x >> 5;
#pragma unroll
  for (int i = 0; i < 4; i++)
    T[ty + i * 8][tx] = aw[(k0 + ty + i * 8) * 4096 + j0 + tx];
  __syncthreads();
#pragma unroll
  for (int i = 0; i < 4; i++)
    awT[(size_t)(j0 + ty + i * 8) * 256 + k0 + tx] = f2bf(T[tx][ty + i * 8]);
}

// ---------------- stage 1: proj16 = bf16(x @ pw + pb)  (16384x1024x256) ----------
// block: 64 rows x 256 cols. 4 waves, each 64 rows x 64 cols (2x2 acc tiles).
// A staged per 128-k chunk in frag-contiguous LDS; B register-direct from pwT (L2).
__global__ __launch_bounds__(256) void k_proj_mfma(const float* __restrict__ x,
                                                   const unsigned short* __restrict__ pwT,
                                                   const float* __restrict__ pb,
                                                   unsigned short* __restrict__ proj16) {
  __shared__ unsigned short As[16 * 64 * 8];  // (kk2*64 + row)*8, 16 KiB
  const int m0 = blockIdx.x * 64;
  const int t = threadIdx.x;
  const int w = t >> 6, lane = t & 63, ln31 = lane & 31, kh = lane >> 5;
  const int c0 = w * 64;

  f32x16 acc00, acc01, acc10, acc11;
#pragma unroll
  for (int r = 0; r < 16; r++) { acc00[r] = 0.f; acc01[r] = 0.f; acc10[r] = 0.f; acc11[r] = 0.f; }

  const unsigned short* bp0 = pwT + (size_t)(c0 + ln31) * E_ + kh * 8;
  const unsigned short* bp1 = bp0 + (size_t)32 * E_;

  for (int kc = 0; kc < E_; kc += 128) {
#pragma unroll
    for (int i = 0; i < 8; i++) {
      int c = t + i * 256;
      int row = c >> 5, pos = c & 31;
      float4 v = *(const float4*)(x + (size_t)(m0 + row) * E_ + kc + pos * 4);
      us4 h;
      h[0] = f2bf(v.x); h[1] = f2bf(v.y); h[2] = f2bf(v.z); h[3] = f2bf(v.w);
      *(us4*)&As[((pos >> 1) * 64 + row) * 8 + (pos & 1) * 4] = h;
    }
    __syncthreads();
#pragma unroll
    for (int kk = 0; kk < 8; kk++) {
      bf16x8 a0 = *(const bf16x8*)&As[((2 * kk + kh) * 64 + ln31) * 8];
      bf16x8 a1 = *(const bf16x8*)&As[((2 * kk + kh) * 64 + 32 + ln31) * 8];
      bf16x8 b0 = *(const bf16x8*)(bp0 + kc + kk * 16);
      bf16x8 b1 = *(const bf16x8*)(bp1 + kc + kk * 16);
      acc00 = __builtin_amdgcn_mfma_f32_32x32x16_bf16(a0, b0, acc00, 0, 0, 0);
      acc01 = __builtin_amdgcn_mfma_f32_32x32x16_bf16(a0, b1, acc01, 0, 0, 0);
      acc10 = __builtin_amdgcn_mfma_f32_32x32x16_bf16(a1, b0, acc10, 0, 0, 0);
      acc11 = __builtin_amdgcn_mfma_f32_32x32x16_bf16(a1, b1, acc11, 0, 0, 0);
    }
    __syncthreads();
  }
  float pb0 = pb[c0 + ln31], pb1 = pb[c0 + 32 + ln31];
#pragma unroll
  for (int r = 0; r < 16; r++) {
    int rl = (r & 3) + 8 * (r >> 2) + 4 * kh;
    size_t g0 = (size_t)(m0 + rl) * P_;
    size_t g1 = (size_t)(m0 + 32 + rl) * P_;
    proj16[g0 + c0 + ln31]      = f2bf(acc00[r] + pb0);
    proj16[g0 + c0 + 32 + ln31] = f2bf(acc01[r] + pb1);
    proj16[g1 + c0 + ln31]      = f2bf(acc10[r] + pb0);
    proj16[g1 + c0 + 32 + ln31] = f2bf(acc11[r] + pb1);
  }
}

// ---------------- stage 2: conv-as-3-shift-GEMM -> rep16 (16384x768x256) ---------
// block: 64 rows x 256 cols. Stage 66 proj16 rows once; 3 shift-GEMMs (K=256)
// accumulate into one acc. B register-direct from wtT (L2).
__global__ __launch_bounds__(256) void k_conv_mfma(const unsigned short* __restrict__ proj16,
                                                   const unsigned short* __restrict__ wtT,
                                                   const float* __restrict__ cb,
                                                   const int* __restrict__ seq,
                                                   unsigned short* __restrict__ rep16) {
  __shared__ unsigned short As[32 * 66 * 8];  // (kk2*66 + row)*8, 33 KiB
  const int m0 = blockIdx.x * 64;
  const int bb = m0 >> 9, s0 = m0 & 511;
  const int t = threadIdx.x;
  const int w = t >> 6, lane = t & 63, ln31 = lane & 31, kh = lane >> 5;
  const int c0 = w * 64;

  // stage 66 rows x 256 k of proj16 (rows past batch end -> 0)
#pragma unroll
  for (int i = 0; i < 9; i++) {
    int c = t + i * 256;
    if (c < 2112) {
      int row = c >> 5, kk2 = c & 31;
      us8 v = {0, 0, 0, 0, 0, 0, 0, 0};
      if (s0 + row <= 511)
        v = *(const us8*)(proj16 + (size_t)(bb * S_ + s0 + row) * P_ + kk2 * 8);
      *(us8*)&As[(kk2 * 66 + row) * 8] = v;
    }
  }
  __syncthreads();

  f32x16 acc00, acc01, acc10, acc11;
#pragma unroll
  for (int r = 0; r < 16; r++) { acc00[r] = 0.f; acc01[r] = 0.f; acc10[r] = 0.f; acc11[r] = 0.f; }

  const unsigned short* bbase0 = wtT + (size_t)(c0 + ln31) * 768 + kh * 8;
  const unsigned short* bbase1 = bbase0 + (size_t)32 * 768;

#pragma unroll
  for (int k = 0; k < 3; k++) {
#pragma unroll
    for (int kk = 0; kk < 16; kk++) {
      bf16x8 a0 = *(const bf16x8*)&As[((2 * kk + kh) * 66 + k + ln31) * 8];
      bf16x8 a1 = *(const bf16x8*)&As[((2 * kk + kh) * 66 + k + 32 + ln31) * 8];
      bf16x8 b0 = *(const bf16x8*)(bbase0 + k * 256 + kk * 16);
      bf16x8 b1 = *(const bf16x8*)(bbase1 + k * 256 + kk * 16);
      acc00 = __builtin_amdgcn_mfma_f32_32x32x16_bf16(a0, b0, acc00, 0, 0, 0);
      acc01 = __builtin_amdgcn_mfma_f32_32x32x16_bf16(a0, b1, acc01, 0, 0, 0);
      acc10 = __builtin_amdgcn_mfma_f32_32x32x16_bf16(a1, b0, acc10, 0, 0, 0);
      acc11 = __builtin_amdgcn_mfma_f32_32x32x16_bf16(a1, b1, acc11, 0, 0, 0);
    }
  }

  int l = seq[bb];
  float cb0 = cb[c0 + ln31], cb1 = cb[c0 + 32 + ln31];
#pragma unroll
  for (int r = 0; r < 16; r++) {
    int rl = (r & 3) + 8 * (r >> 2) + 4 * kh;
    int s_a = s0 + rl, s_b = s0 + 32 + rl;
    float ma = (s_a >= 1 && s_a <= 509 && s_a < l - 1) ? 1.f : 0.f;
    float mb = (s_b >= 1 && s_b <= 509 && s_b < l - 1) ? 1.f : 0.f;
    size_t g0 = (size_t)(m0 + rl) * P_;
    size_t g1 = (size_t)(m0 + 32 + rl) * P_;
    rep16[g0 + c0 + ln31]      = f2bf(fmaxf(acc00[r] + cb0, 0.f) * ma);
    rep16[g0 + c0 + 32 + ln31] = f2bf(fmaxf(acc01[r] + cb1, 0.f) * ma);
    rep16[g1 + c0 + ln31]      = f2bf(fmaxf(acc10[r] + cb0, 0.f) * mb);
    rep16[g1 + c0 + 32 + ln31] = f2bf(fmaxf(acc11[r] + cb1, 0.f) * mb);
  }
}

// ---------------- stage 3: MFMA logits GEMM + exp + h-fold -----------------------
__global__ __launch_bounds__(256) void k_attn_mfma(const unsigned short* __restrict__ rep16,
                                                   const unsigned short* __restrict__ awT,
                                                   const float* __restrict__ ab,
                                                   float* __restrict__ E) {
  __shared__ unsigned short As[64][264];
  const int m0 = blockIdx.x * 64;
  const int q0 = blockIdx.y * 128;
  const int t = threadIdx.x;
  const int w = t >> 6;
  const int lane = t & 63;
  const int ln31 = lane & 31;
  const int khalf = (lane >> 5) * 8;

#pragma unroll
  for (int i = 0; i < 8; i++) {
    int flat = i * 256 + t;
    int r = flat >> 5;
    int g = (flat & 31) * 8;
    us8 v = *(const us8*)(rep16 + (size_t)(m0 + r) * 256 + g);
    *(us8*)&As[r][g] = v;
  }
  __syncthreads();

  const int qcol = q0 + w * 32 + ln31;
  const unsigned short* bcol = awT + (size_t)qcol * 256 + khalf;

  float ef0[16], ef1[16];
#pragma unroll
  for (int r = 0; r < 16; r++) { ef0[r] = 0.f; ef1[r] = 0.f; }

  for (int h = 0; h < HH; h++) {
    const unsigned short* bh = bcol + (size_t)h * 512 * 256;
    f32x16 acc0, acc1;
#pragma unroll
    for (int r = 0; r < 16; r++) { acc0[r] = 0.f; acc1[r] = 0.f; }

#pragma unroll
    for (int kc = 0; kc < 256; kc += 16) {
      bf16x8 a0 = *(const bf16x8*)&As[ln31][kc + khalf];
      bf16x8 a1 = *(const bf16x8*)&As[32 + ln31][kc + khalf];
      bf16x8 b  = *(const bf16x8*)(bh + kc);
      acc0 = __builtin_amdgcn_mfma_f32_32x32x16_bf16(a0, b, acc0, 0, 0, 0);
      acc1 = __builtin_amdgcn_mfma_f32_32x32x16_bf16(a1, b, acc1, 0, 0, 0);
    }
    float bias = ab[h * 512 + qcol];
#pragma unroll
    for (int r = 0; r < 16; r++) {
      ef0[r] += __expf(acc0[r] + bias);
      ef1[r] += __expf(acc1[r] + bias);
    }
  }
  const int rbase = m0 + 4 * (lane >> 5);
#pragma unroll
  for (int r = 0; r < 16; r++) {
    int row0 = rbase + (r & 3) + 8 * (r >> 2);
    E[(size_t)row0 * 512 + qcol] = ef0[r];
    E[(size_t)(row0 + 32) * 512 + qcol] = ef1[r];
  }
}

// ---------------- stage 4a: row sums Z[row] = sum_q E[row][q] --------------------
__global__ __launch_bounds__(256) void k_z(const float* __restrict__ E,
                                           float* __restrict__ Z) {
  int row = blockIdx.x * 4 + (threadIdx.x >> 6);
  int lane = threadIdx.x & 63;
  float s = 0.f;
#pragma unroll
  for (int j = 0; j < 8; j++) s += E[(size_t)row * 512 + j * 64 + lane];
#pragma unroll
  for (int m = 32; m > 0; m >>= 1) s += __shfl_xor(s, m, 64);
  if (lane == 0) Z[row] = s;
}

// ---------------- zero wB (16K floats) + repA (8K floats), contiguous ------------
__global__ __launch_bounds__(256) void k_zero(float* __restrict__ p) {
  p[blockIdx.x * 256 + threadIdx.x] = 0.f;
}

// ---------------- stage 4b: w[b,q] = (1/H) sum_s E[b,s,q]/Z[b,s] -----------------
__global__ __launch_bounds__(512) void k_w(const float* __restrict__ E,
                                           const float* __restrict__ Z,
                                           float* __restrict__ wB) {
  __shared__ float rZ[64];
  int b = blockIdx.x, c = blockIdx.y, t = threadIdx.x;
  int s0 = c * 64;
  if (t < 64) rZ[t] = 1.0f / Z[b * 512 + s0 + t];
  __syncthreads();
  float acc = 0.f;
  for (int s = 0; s < 64; s++) acc += E[(size_t)(b * 512 + s0 + s) * 512 + t] * rZ[s];
  atomicAdd(&wB[b * 512 + t], acc * (1.0f / HH));
}

// ---------------- stage 5a: repA[b,p] = sum_q w[b,q] * rep16[b,q,p] --------------
__global__ __launch_bounds__(256) void k_final_a(const unsigned short* __restrict__ rep16,
                                                 const float* __restrict__ wB,
                                                 float* __restrict__ repA) {
  __shared__ float wS[64];
  int b = blockIdx.x, qc = blockIdx.y, t = threadIdx.x;
  if (t < 64) wS[t] = wB[b * 512 + qc * 64 + t];
  __syncthreads();
  float acc = 0.f;
  const unsigned short* base = rep16 + (size_t)(b * 512 + qc * 64) * 256 + t;
#pragma unroll 8
  for (int q = 0; q < 64; q++) acc += wS[q] * bf2f(base[(size_t)q * 256]);
  atomicAdd(&repA[b * 256 + t], acc);
}

// ---------------- stage 5b: heads -> probs + argmax ------------------------------
__global__ __launch_bounds__(128) void k_final_b(const float* __restrict__ repA,
                                                 const float* __restrict__ c1w,
                                                 const float* __restrict__ c1b,
                                                 const float* __restrict__ c2w,
                                                 const float* __restrict__ c2b,
                                                 float* __restrict__ out) {
  __shared__ float hS[128];
  __shared__ float clsS[2];
  int b = blockIdx.x, t = threadIdx.x;
  float acc = c1b[t];
  for (int p = 0; p < 256; p++) acc += repA[b * 256 + p] * c1w[p * 128 + t];
  hS[t] = acc > 0.f ? acc : 0.01f * acc;
  __syncthreads();
  if (t < 2) {
    float a2 = c2b[t];
    for (int j = 0; j < 128; j++) a2 += hS[j] * c2w[j * 2 + t];
    clsS[t] = a2;
  }
  __syncthreads();
  if (t == 0) {
    float c0 = clsS[0], c1 = clsS[1];
    float m = fmaxf(c0, c1);
    float e0 = __expf(c0 - m), e1 = __expf(c1 - m);
    float inv = 1.0f / (e0 + e1);
    float p0 = e0 * inv, p1 = e1 * inv;
    out[b * 2 + 0] = p0;
    out[b * 2 + 1] = p1;
    out[B_ * 2 + b] = (p1 > p0) ? 1.0f : 0.0f;
  }
}

extern "C" void kernel_launch(void* const* d_in, const int* in_sizes, int n_in,
                              void* d_out, int out_size, void* d_ws, size_t ws_size,
                              hipStream_t stream) {
  const float* x   = (const float*)d_in[0];
  const int*   seq = (const int*)d_in[1];
  const float* pw  = (const float*)d_in[2];
  const float* pb  = (const float*)d_in[3];
  const float* cw  = (const float*)d_in[4];
  const float* cb  = (const float*)d_in[5];
  const float* aw  = (const float*)d_in[6];
  const float* ab  = (const float*)d_in[7];
  const float* c1w = (const float*)d_in[8];
  const float* c1b = (const float*)d_in[9];
  const float* c2w = (const float*)d_in[10];
  const float* c2b = (const float*)d_in[11];
  float* out = (float*)d_out;

  char* ws = (char*)d_ws;
  // proj16 (8 MiB) overlaps E (32 MiB): proj16 dies (k_conv) before E written (k_attn)
  unsigned short* proj16 = (unsigned short*)(ws);
  float*          E      = (float*)(ws);                              // 32 MiB @ 0
  unsigned short* rep16  = (unsigned short*)(ws + (size_t)33554432);  // 8 MiB
  unsigned short* pwT    = (unsigned short*)(ws + (size_t)41943040);  // 512 KiB
  unsigned short* wtT    = (unsigned short*)(ws + (size_t)42467328);  // 384 KiB
  unsigned short* awT    = (unsigned short*)(ws + (size_t)42860544);  // 2 MiB
  float*          Z      = (float*)(ws + (size_t)44957696);           // 64 KiB
  float*          wB     = (float*)(ws + (size_t)45023232);           // 64 KiB
  float*          repA   = (float*)(ws + (size_t)45088768);           // 32 KiB (right after wB)

  k_wtT<<<dim3(256, 3), 256, 0, stream>>>(cw, wtT);
  k_pwT<<<dim3(8, 32), 256, 0, stream>>>(pw, pwT);
  k_awT<<<dim3(128, 8), 256, 0, stream>>>(aw, awT);
  k_proj_mfma<<<256, 256, 0, stream>>>(x, pwT, pb, proj16);
  k_conv_mfma<<<256, 256, 0, stream>>>(proj16, wtT, cb, seq, rep16);
  k_attn_mfma<<<dim3(256, 4), 256, 0, stream>>>(rep16, awT, ab, E);
  k_z<<<4096, 256, 0, stream>>>(E, Z);
  k_zero<<<96, 256, 0, stream>>>(wB);  // zeroes wB (16K) + repA (8K), contiguous
  k_w<<<dim3(32, 8), 512, 0, stream>>>(E, Z, wB);
  k_final_a<<<dim3(32, 8), 256, 0, stream>>>(rep16, wB, repA);
  k_final_b<<<32, 128, 0, stream>>>(repA, c1w, c1b, c2w, c2b, out);
}